// Round 1
// baseline (210.764 us; speedup 1.0000x reference)
//
#include <hip/hip_runtime.h>

#define BATCH 8
#define NPTS  8192
#define TN    4      // outer points per thread
#define CHUNK 512    // inner points per block (per chunk)
#define TPB   256

// ---------------------------------------------------------------------------
// init: fill per-point min slots with +inf (as int bits)
// ---------------------------------------------------------------------------
__global__ void init_mins(unsigned int* __restrict__ mins, int n) {
    int i = blockIdx.x * blockDim.x + threadIdx.x;
    if (i < n) mins[i] = 0x7F800000u;  // +inf
}

// ---------------------------------------------------------------------------
// For each outer point a (TN per thread), scan CHUNK inner points b, keep
// running min of squared distance, atomicMin into out_min[batch*NPTS + n].
// Inner-loop addresses are block-uniform -> compiler emits scalar loads.
// ---------------------------------------------------------------------------
__global__ __launch_bounds__(TPB)
void chamfer_dir(const float* __restrict__ A,
                 const float* __restrict__ Bp,
                 int* __restrict__ out_min) {
    const int batch = blockIdx.z;
    const int chunk = blockIdx.x;            // 0 .. NPTS/CHUNK-1
    const int tileN = blockIdx.y;            // 0 .. NPTS/(TPB*TN)-1
    const int n0 = tileN * (TPB * TN) + threadIdx.x * TN;

    const float* a = A + ((size_t)batch * NPTS + n0) * 3;
    float ax[TN], ay[TN], az[TN], mn[TN];
#pragma unroll
    for (int t = 0; t < TN; ++t) {
        ax[t] = a[t * 3 + 0];
        ay[t] = a[t * 3 + 1];
        az[t] = a[t * 3 + 2];
        mn[t] = INFINITY;
    }

    const float* bp = Bp + ((size_t)batch * NPTS + chunk * CHUNK) * 3;
#pragma unroll 4
    for (int k = 0; k < CHUNK; ++k) {
        const float bx = bp[3 * k + 0];
        const float by = bp[3 * k + 1];
        const float bz = bp[3 * k + 2];
#pragma unroll
        for (int t = 0; t < TN; ++t) {
            const float dx = ax[t] - bx;
            const float dy = ay[t] - by;
            const float dz = az[t] - bz;
            const float d = dx * dx + dy * dy + dz * dz;  // mul + 2 fma
            mn[t] = fminf(mn[t], d);
        }
    }

#pragma unroll
    for (int t = 0; t < TN; ++t)
        atomicMin(&out_min[batch * NPTS + n0 + t], __float_as_int(mn[t]));
}

// ---------------------------------------------------------------------------
// deterministic single-block sum of all 2*BATCH*NPTS mins -> scalar
// ---------------------------------------------------------------------------
__global__ void final_sum(const int* __restrict__ mins, float* __restrict__ out) {
    const int n = 2 * BATCH * NPTS;
    float s = 0.f;
    for (int i = threadIdx.x; i < n; i += blockDim.x)
        s += __int_as_float(mins[i]);
#pragma unroll
    for (int off = 32; off; off >>= 1)
        s += __shfl_down(s, off, 64);
    __shared__ float wsum[16];
    const int lane = threadIdx.x & 63;
    const int wid = threadIdx.x >> 6;
    if (lane == 0) wsum[wid] = s;
    __syncthreads();
    if (threadIdx.x == 0) {
        float tot = 0.f;
        const int nw = blockDim.x >> 6;
        for (int w = 0; w < nw; ++w) tot += wsum[w];
        *out = tot;
    }
}

extern "C" void kernel_launch(void* const* d_in, const int* in_sizes, int n_in,
                              void* d_out, int out_size, void* d_ws, size_t ws_size,
                              hipStream_t stream) {
    const float* preds = (const float*)d_in[0];  // [B, M, 3]
    const float* gts   = (const float*)d_in[1];  // [B, N, 3]
    int* mins = (int*)d_ws;  // [0, B*N): min over preds per gt (loss_2)
                             // [B*N, 2*B*N): min over gts per pred (loss_1)

    const int total = 2 * BATCH * NPTS;
    init_mins<<<(total + 255) / 256, 256, 0, stream>>>((unsigned int*)mins, total);

    dim3 grid(NPTS / CHUNK, NPTS / (TPB * TN), BATCH);  // 16 x 8 x 8 = 1024 blocks
    // loss_2: for each gt point, min over preds
    chamfer_dir<<<grid, TPB, 0, stream>>>(gts, preds, mins);
    // loss_1: for each pred point, min over gts
    chamfer_dir<<<grid, TPB, 0, stream>>>(preds, gts, mins + BATCH * NPTS);

    final_sum<<<1, 1024, 0, stream>>>(mins, (float*)d_out);
}

// Round 2
// 168.702 us; speedup vs baseline: 1.2493x; 1.2493x over previous
//
#include <hip/hip_runtime.h>

#define BATCH 8
#define NPTS  8192
#define TN    4      // rows per thread
#define CHUNK 512    // columns per block
#define TPB   256

// ws layout (floats/uints, 4B each):
//   [0      , 65536)  haa  : 0.5*|gt|^2   per gt point
//   [65536  ,131072)  hbb  : 0.5*|pred|^2 per pred point
//   [131072 ,196608)  smax1: mapped max_m (gt_n . pred_m - hbb_m)   (rows=gts)
//   [196608 ,262144)  smax2: mapped max_n (pred_m . gt_n - haa_n)   (rows=preds)
// total 1 MiB

#define NPT_TOT (BATCH * NPTS)  // 65536

// order-preserving float->uint map: u = bits ^ (bits<0 ? 0xFFFFFFFF : 0x80000000)
__device__ __forceinline__ unsigned int map_f(float f) {
    int i = __float_as_int(f);
    return (unsigned int)(i ^ ((i >> 31) | 0x80000000));
}
__device__ __forceinline__ float unmap_f(unsigned int u) {
    int i = (u & 0x80000000u) ? (int)(u ^ 0x80000000u) : (int)~u;
    return __int_as_float(i);
}

// ---------------------------------------------------------------------------
// prepass: half-squared-norms for both clouds + zero-init the smax slots
// ---------------------------------------------------------------------------
__global__ void prepass(const float* __restrict__ gts,
                        const float* __restrict__ preds,
                        float* __restrict__ ws) {
    int i = blockIdx.x * blockDim.x + threadIdx.x;
    if (i < NPT_TOT) {
        float x = gts[3 * i], y = gts[3 * i + 1], z = gts[3 * i + 2];
        ws[i] = 0.5f * (x * x + y * y + z * z);
    } else if (i < 2 * NPT_TOT) {
        int j = i - NPT_TOT;
        float x = preds[3 * j], y = preds[3 * j + 1], z = preds[3 * j + 2];
        ws[i] = 0.5f * (x * x + y * y + z * z);
    } else if (i < 4 * NPT_TOT) {
        ((unsigned int*)ws)[i] = 0u;  // mapped -NaN, below every real
    }
}

// ---------------------------------------------------------------------------
// per row a: running max over columns b of  s = a.b - 0.5|b|^2
// (min distance = 2*(0.5|a|^2 - max s)). 4 VALU ops per pair.
// Column loads are block-uniform -> scalar pipe.
// ---------------------------------------------------------------------------
__global__ __launch_bounds__(TPB)
void chamfer_smax(const float* __restrict__ A,
                  const float* __restrict__ Bc,
                  const float* __restrict__ hb,
                  unsigned int* __restrict__ smax) {
    const int batch = blockIdx.z;
    const int chunk = blockIdx.x;
    const int tileN = blockIdx.y;
    const int n0 = tileN * (TPB * TN) + threadIdx.x * TN;

    const float* a = A + ((size_t)batch * NPTS + n0) * 3;
    float ax[TN], ay[TN], az[TN], mx[TN];
#pragma unroll
    for (int t = 0; t < TN; ++t) {
        ax[t] = a[t * 3 + 0];
        ay[t] = a[t * 3 + 1];
        az[t] = a[t * 3 + 2];
        mx[t] = -INFINITY;
    }

    const float* bp  = Bc + ((size_t)batch * NPTS + chunk * CHUNK) * 3;
    const float* hbp = hb + (size_t)batch * NPTS + chunk * CHUNK;
#pragma unroll 8
    for (int k = 0; k < CHUNK; ++k) {
        const float bx = bp[3 * k + 0];
        const float by = bp[3 * k + 1];
        const float bz = bp[3 * k + 2];
        const float h  = hbp[k];
#pragma unroll
        for (int t = 0; t < TN; ++t) {
            float s = fmaf(az[t], bz, -h);   // fma with negate modifier
            s = fmaf(ay[t], by, s);
            s = fmaf(ax[t], bx, s);
            mx[t] = fmaxf(mx[t], s);
        }
    }

#pragma unroll
    for (int t = 0; t < TN; ++t)
        atomicMax(&smax[batch * NPTS + n0 + t], map_f(mx[t]));
}

// ---------------------------------------------------------------------------
// loss = 2 * [ sum_n (haa_n - smax1_n) + sum_m (hbb_m - smax2_m) ]
// deterministic single-block sum
// ---------------------------------------------------------------------------
__global__ void final_sum(const float* __restrict__ ws, float* __restrict__ out) {
    const float* haa = ws;
    const float* hbb = ws + NPT_TOT;
    const unsigned int* s1 = (const unsigned int*)(ws + 2 * NPT_TOT);
    const unsigned int* s2 = (const unsigned int*)(ws + 3 * NPT_TOT);

    float s = 0.f;
    for (int i = threadIdx.x; i < NPT_TOT; i += blockDim.x)
        s += haa[i] - unmap_f(s1[i]);
    for (int i = threadIdx.x; i < NPT_TOT; i += blockDim.x)
        s += hbb[i] - unmap_f(s2[i]);

#pragma unroll
    for (int off = 32; off; off >>= 1)
        s += __shfl_down(s, off, 64);
    __shared__ float wsum[16];
    const int lane = threadIdx.x & 63;
    const int wid = threadIdx.x >> 6;
    if (lane == 0) wsum[wid] = s;
    __syncthreads();
    if (threadIdx.x == 0) {
        float tot = 0.f;
        const int nw = blockDim.x >> 6;
        for (int w = 0; w < nw; ++w) tot += wsum[w];
        *out = 2.0f * tot;
    }
}

extern "C" void kernel_launch(void* const* d_in, const int* in_sizes, int n_in,
                              void* d_out, int out_size, void* d_ws, size_t ws_size,
                              hipStream_t stream) {
    const float* preds = (const float*)d_in[0];  // [B, M, 3]
    const float* gts   = (const float*)d_in[1];  // [B, N, 3]
    float* ws = (float*)d_ws;

    prepass<<<(4 * NPT_TOT + TPB - 1) / TPB, TPB, 0, stream>>>(gts, preds, ws);

    dim3 grid(NPTS / CHUNK, NPTS / (TPB * TN), BATCH);  // 16 x 8 x 8
    unsigned int* s1 = (unsigned int*)(ws + 2 * NPT_TOT);
    unsigned int* s2 = (unsigned int*)(ws + 3 * NPT_TOT);
    // rows = gts, cols = preds: per-gt max_m (a.b - hbb)  -> loss_2
    chamfer_smax<<<grid, TPB, 0, stream>>>(gts, preds, ws + NPT_TOT, s1);
    // rows = preds, cols = gts: per-pred max_n (a.b - haa) -> loss_1
    chamfer_smax<<<grid, TPB, 0, stream>>>(preds, gts, ws, s2);

    final_sum<<<1, 1024, 0, stream>>>(ws, (float*)d_out);
}

// Round 3
// 103.056 us; speedup vs baseline: 2.0451x; 1.6370x over previous
//
#include <hip/hip_runtime.h>
#include <hip/hip_bf16.h>

#define BATCH 8
#define NPTS  8192
#define NPT_TOT (BATCH * NPTS)   // 65536 points per cloud

typedef __attribute__((ext_vector_type(8)))  short short8;
typedef __attribute__((ext_vector_type(16))) float float16;
typedef unsigned int uint32;

// order-preserving float->uint map for atomicMax
__device__ __forceinline__ uint32 map_f(float f) {
    int i = __float_as_int(f);
    return (uint32)(i ^ ((i >> 31) | 0x80000000));
}
__device__ __forceinline__ float unmap_f(uint32 u) {
    int i = (u & 0x80000000u) ? (int)(u ^ 0x80000000u) : (int)~u;
    return __int_as_float(i);
}

__device__ __forceinline__ unsigned short bf16_of(float f) {
    __hip_bfloat16 h = __float2bfloat16(f);
    return *reinterpret_cast<unsigned short*>(&h);
}
__device__ __forceinline__ float f_of_bf16(unsigned short u) {
    __hip_bfloat16 h = *reinterpret_cast<__hip_bfloat16*>(&u);
    return __bfloat162float(h);
}
__device__ __forceinline__ uint32 pk(unsigned short lo, unsigned short hi) {
    return (uint32)lo | ((uint32)hi << 16);
}

// ---------------------------------------------------------------------------
// prepass: per point build
//   A-form K slots: [xh yh zh | xl yl zl | xh yh zh | xl yl zl | 1 1 0 0]
//   B-form K slots: [xh yh zh | xh yh zh | xl yl zl | xl yl zl | -hh -hl 0 0]
// so sum_k A[k](a)*B[k](b) = (ah+al).(bh+bl) - h_b  (h = 0.5|b|^2)
// Also: exact fp32 half-norms, and zero-init both smax arrays.
// ---------------------------------------------------------------------------
__global__ __launch_bounds__(256)
void prepass(const float* __restrict__ gts, const float* __restrict__ preds,
             float* __restrict__ norms, uint32* __restrict__ smax,
             unsigned short* __restrict__ AG, unsigned short* __restrict__ BG,
             unsigned short* __restrict__ AP, unsigned short* __restrict__ BP)
{
    int i = blockIdx.x * blockDim.x + threadIdx.x;
    if (i >= 2 * NPT_TOT) return;
    const bool isGt = i < NPT_TOT;
    const int j = isGt ? i : i - NPT_TOT;
    const float* src = (isGt ? gts : preds) + 3 * (size_t)j;
    const float x = src[0], y = src[1], z = src[2];
    const float h = 0.5f * (x * x + y * y + z * z);
    norms[i] = h;       // [haa | hbb]
    smax[i]  = 0u;      // mapped: below every real value

    const unsigned short xh = bf16_of(x), yh = bf16_of(y), zh = bf16_of(z);
    const unsigned short xl = bf16_of(x - f_of_bf16(xh));
    const unsigned short yl = bf16_of(y - f_of_bf16(yh));
    const unsigned short zl = bf16_of(z - f_of_bf16(zh));
    const unsigned short nhh = bf16_of(-h);
    const unsigned short nhl = bf16_of(-h - f_of_bf16(nhh));
    const unsigned short one = 0x3F80;

    unsigned short* A = (isGt ? AG : AP) + (size_t)j * 16;
    unsigned short* Bf = (isGt ? BG : BP) + (size_t)j * 16;

    uint4 av0 = { pk(xh, yh), pk(zh, xl), pk(yl, zl), pk(xh, yh) };
    uint4 av1 = { pk(zh, xl), pk(yl, zl), pk(one, one), 0u };
    *reinterpret_cast<uint4*>(A)     = av0;
    *reinterpret_cast<uint4*>(A + 8) = av1;

    uint4 bv0 = { pk(xh, yh), pk(zh, xh), pk(yh, zh), pk(xl, yl) };
    uint4 bv1 = { pk(zl, xl), pk(yl, zl), pk(nhh, nhl), 0u };
    *reinterpret_cast<uint4*>(Bf)     = bv0;
    *reinterpret_cast<uint4*>(Bf + 8) = bv1;
}

// ---------------------------------------------------------------------------
// main: rows (A-form) x cols (B-form), 32x32x16 bf16 MFMA, running max over
// columns of s = a.b - h_b, then cross-lane max + atomicMax per row.
// Wave: 2 row-tiles (64 rows). Block: 4 waves = 256 rows. Grid.x: col chunks.
// ---------------------------------------------------------------------------
__global__ __launch_bounds__(256)
void chamfer_mfma(const unsigned short* __restrict__ Arows,
                  const unsigned short* __restrict__ Bcols,
                  uint32* __restrict__ smax)
{
    const int lane  = threadIdx.x & 63;
    const int wid   = threadIdx.x >> 6;
    const int batch = blockIdx.z;
    const int row0  = blockIdx.y * 256 + wid * 64;
    const int colbase = blockIdx.x * (NPTS / 4);   // 2048 cols per block

    const int lr = lane & 31;        // row/col within tile
    const int lg = lane >> 5;        // K-half group

    const short8 a0 = *reinterpret_cast<const short8*>(
        Arows + ((size_t)(batch * NPTS + row0 + lr)) * 16 + lg * 8);
    const short8 a1 = *reinterpret_cast<const short8*>(
        Arows + ((size_t)(batch * NPTS + row0 + 32 + lr)) * 16 + lg * 8);

    float16 mx0, mx1;
#pragma unroll
    for (int j = 0; j < 16; ++j) { mx0[j] = -INFINITY; mx1[j] = -INFINITY; }

    const short8* bptr = reinterpret_cast<const short8*>(
        Bcols + ((size_t)(batch * NPTS + colbase + lr)) * 16 + lg * 8);
    const float16 zero16 = {0.f, 0.f, 0.f, 0.f, 0.f, 0.f, 0.f, 0.f,
                            0.f, 0.f, 0.f, 0.f, 0.f, 0.f, 0.f, 0.f};

    // 64 col-tiles of 32, processed 2 at a time; tile stride = 32 pts * 2 short8
    for (int ct = 0; ct < NPTS / 4 / 32; ct += 2) {
        const short8 b0 = bptr[(size_t)ct * 64];
        const short8 b1 = bptr[(size_t)(ct + 1) * 64];
        float16 d00 = __builtin_amdgcn_mfma_f32_32x32x16_bf16(a0, b0, zero16, 0, 0, 0);
        float16 d01 = __builtin_amdgcn_mfma_f32_32x32x16_bf16(a0, b1, zero16, 0, 0, 0);
        float16 d10 = __builtin_amdgcn_mfma_f32_32x32x16_bf16(a1, b0, zero16, 0, 0, 0);
        float16 d11 = __builtin_amdgcn_mfma_f32_32x32x16_bf16(a1, b1, zero16, 0, 0, 0);
#pragma unroll
        for (int j = 0; j < 16; ++j) {
            mx0[j] = fmaxf(fmaxf(d00[j], d01[j]), mx0[j]);   // v_max3
            mx1[j] = fmaxf(fmaxf(d10[j], d11[j]), mx1[j]);
        }
    }

    // cross-lane max over the 32 columns held by each half-wave group
#pragma unroll
    for (int m = 1; m <= 16; m <<= 1) {
#pragma unroll
        for (int j = 0; j < 16; ++j) {
            mx0[j] = fmaxf(mx0[j], __shfl_xor(mx0[j], m, 64));
            mx1[j] = fmaxf(mx1[j], __shfl_xor(mx1[j], m, 64));
        }
    }

    if (lr == 0) {
        const int g4 = lg * 4;
#pragma unroll
        for (int j = 0; j < 16; ++j) {
            const int r = row0 + (j & 3) + 8 * (j >> 2) + g4;  // m74/m101 C/D layout
            atomicMax(&smax[batch * NPTS + r],      map_f(mx0[j]));
            atomicMax(&smax[batch * NPTS + r + 32], map_f(mx1[j]));
        }
    }
}

// ---------------------------------------------------------------------------
// deterministic 2-stage final sum: loss = 2 * sum_i (norms[i] - unmap(smax[i]))
// ---------------------------------------------------------------------------
__global__ __launch_bounds__(256)
void final_stage1(const float* __restrict__ norms, const uint32* __restrict__ smax,
                  float* __restrict__ partials)
{
    const int base = blockIdx.x * 1024;
    float s = 0.f;
    for (int k = threadIdx.x; k < 1024; k += 256) {
        const int i = base + k;
        s += norms[i] - unmap_f(smax[i]);
    }
#pragma unroll
    for (int off = 32; off; off >>= 1) s += __shfl_down(s, off, 64);
    __shared__ float ws4[4];
    if ((threadIdx.x & 63) == 0) ws4[threadIdx.x >> 6] = s;
    __syncthreads();
    if (threadIdx.x == 0) partials[blockIdx.x] = (ws4[0] + ws4[1]) + (ws4[2] + ws4[3]);
}

__global__ void final_stage2(const float* __restrict__ partials, float* __restrict__ out)
{
    float s = partials[threadIdx.x] + partials[threadIdx.x + 64];
#pragma unroll
    for (int off = 32; off; off >>= 1) s += __shfl_down(s, off, 64);
    if (threadIdx.x == 0) *out = 2.0f * s;
}

extern "C" void kernel_launch(void* const* d_in, const int* in_sizes, int n_in,
                              void* d_out, int out_size, void* d_ws, size_t ws_size,
                              hipStream_t stream) {
    const float* preds = (const float*)d_in[0];  // [B, M, 3]
    const float* gts   = (const float*)d_in[1];  // [B, N, 3]

    char* w = (char*)d_ws;
    float*  norms = (float*)w;                                   // 512 KiB  [haa|hbb]
    uint32* smax  = (uint32*)(w + 8 * (size_t)NPT_TOT);          // 512 KiB  [smax1|smax2]
    unsigned short* AG = (unsigned short*)(w + 16 * (size_t)NPT_TOT);  // 2 MiB each
    unsigned short* BG = AG + 16 * (size_t)NPT_TOT;
    unsigned short* AP = BG + 16 * (size_t)NPT_TOT;
    unsigned short* BP = AP + 16 * (size_t)NPT_TOT;
    float* partials = (float*)(w + 16 * (size_t)NPT_TOT + 4 * 32 * (size_t)NPT_TOT);

    prepass<<<(2 * NPT_TOT) / 256, 256, 0, stream>>>(gts, preds, norms, smax,
                                                     AG, BG, AP, BP);

    dim3 grid(4, NPTS / 256, BATCH);  // 4 col-chunks x 32 row-groups x 8 batches
    // loss_2: rows = gts, cols = preds (uses h_pred inside B-form)
    chamfer_mfma<<<grid, 256, 0, stream>>>(AG, BP, smax);
    // loss_1: rows = preds, cols = gts
    chamfer_mfma<<<grid, 256, 0, stream>>>(AP, BG, smax + NPT_TOT);

    final_stage1<<<128, 256, 0, stream>>>(norms, smax, partials);
    final_stage2<<<1, 64, 0, stream>>>(partials, (float*)d_out);
}

// Round 4
// 74.520 us; speedup vs baseline: 2.8283x; 1.3829x over previous
//
#include <hip/hip_runtime.h>
#include <hip/hip_bf16.h>

#define BATCH 8
#define NPTS  8192
#define NPT_TOT (BATCH * NPTS)   // 65536 points per cloud

typedef __attribute__((ext_vector_type(8)))  short short8;
typedef __attribute__((ext_vector_type(16))) float float16;
typedef unsigned int uint32;

// order-preserving float->uint map for atomicMax
__device__ __forceinline__ uint32 map_f(float f) {
    int i = __float_as_int(f);
    return (uint32)(i ^ ((i >> 31) | 0x80000000));
}
__device__ __forceinline__ float unmap_f(uint32 u) {
    int i = (u & 0x80000000u) ? (int)(u ^ 0x80000000u) : (int)~u;
    return __int_as_float(i);
}

__device__ __forceinline__ unsigned short bf16_of(float f) {
    __hip_bfloat16 h = __float2bfloat16(f);
    return *reinterpret_cast<unsigned short*>(&h);
}
__device__ __forceinline__ float f_of_bf16(unsigned short u) {
    __hip_bfloat16 h = *reinterpret_cast<__hip_bfloat16*>(&u);
    return __bfloat162float(h);
}
__device__ __forceinline__ uint32 pk(unsigned short lo, unsigned short hi) {
    return (uint32)lo | ((uint32)hi << 16);
}

// ---------------------------------------------------------------------------
// prepass: per point build K-major 16-slot vectors
//   Row-form (A): [xh yh zh | xl yl zl | xh yh zh | xl yl zl | 1 1 0 0]
//   Col-form (B): [xh yh zh | xh yh zh | xl yl zl | xl yl zl | -hh -hl 0 0]
// sum_k Row[k](a)*Col[k](b) = (ah+al).(bh+bl) - 0.5|b|^2
// Also exact fp32 half-norms + zero-init smax.
// ---------------------------------------------------------------------------
__global__ __launch_bounds__(256)
void prepass(const float* __restrict__ gts, const float* __restrict__ preds,
             float* __restrict__ norms, uint32* __restrict__ smax,
             unsigned short* __restrict__ AG, unsigned short* __restrict__ BG,
             unsigned short* __restrict__ AP, unsigned short* __restrict__ BP)
{
    int i = blockIdx.x * blockDim.x + threadIdx.x;
    if (i >= 2 * NPT_TOT) return;
    const bool isGt = i < NPT_TOT;
    const int j = isGt ? i : i - NPT_TOT;
    const float* src = (isGt ? gts : preds) + 3 * (size_t)j;
    const float x = src[0], y = src[1], z = src[2];
    const float h = 0.5f * (x * x + y * y + z * z);
    norms[i] = h;       // [haa | hbb]
    smax[i]  = 0u;      // mapped: below every real value

    const unsigned short xh = bf16_of(x), yh = bf16_of(y), zh = bf16_of(z);
    const unsigned short xl = bf16_of(x - f_of_bf16(xh));
    const unsigned short yl = bf16_of(y - f_of_bf16(yh));
    const unsigned short zl = bf16_of(z - f_of_bf16(zh));
    const unsigned short nhh = bf16_of(-h);
    const unsigned short nhl = bf16_of(-h - f_of_bf16(nhh));
    const unsigned short one = 0x3F80;

    unsigned short* A = (isGt ? AG : AP) + (size_t)j * 16;
    unsigned short* Bf = (isGt ? BG : BP) + (size_t)j * 16;

    uint4 av0 = { pk(xh, yh), pk(zh, xl), pk(yl, zl), pk(xh, yh) };
    uint4 av1 = { pk(zh, xl), pk(yl, zl), pk(one, one), 0u };
    *reinterpret_cast<uint4*>(A)     = av0;
    *reinterpret_cast<uint4*>(A + 8) = av1;

    uint4 bv0 = { pk(xh, yh), pk(zh, xh), pk(yh, zh), pk(xl, yl) };
    uint4 bv1 = { pk(zl, xl), pk(yl, zl), pk(nhh, nhl), 0u };
    *reinterpret_cast<uint4*>(Bf)     = bv0;
    *reinterpret_cast<uint4*>(Bf + 8) = bv1;
}

// ---------------------------------------------------------------------------
// main: SWAPPED operands — streamed col-points are the MFMA A-operand, the
// wave's 64 row-points (2 tiles) are the B-operand. Output col = lane&31 =
// row-point, so each lane's 16 D-regs are 16 col-points for ONE row:
// the column-max is an in-register max3 chain, epilogue is one shfl_xor(32).
// Register double-buffer prefetch hides L2 latency.
// ---------------------------------------------------------------------------
__global__ __launch_bounds__(256)
void chamfer_mfma(const unsigned short* __restrict__ Arows,
                  const unsigned short* __restrict__ Bcols,
                  uint32* __restrict__ smax)
{
    const int lane  = threadIdx.x & 63;
    const int wid   = threadIdx.x >> 6;
    const int batch = blockIdx.z;
    const int row0  = blockIdx.y * 256 + wid * 64;
    const int colbase = blockIdx.x * (NPTS / 4);   // 2048 cols per block

    const int lr = lane & 31;        // point within tile
    const int lg = lane >> 5;        // K-half group

    // row-points as B-operand fragments (K-major per point, lg selects K-half)
    const short8 a0 = *reinterpret_cast<const short8*>(
        Arows + ((size_t)(batch * NPTS + row0 + lr)) * 16 + lg * 8);
    const short8 a1 = *reinterpret_cast<const short8*>(
        Arows + ((size_t)(batch * NPTS + row0 + 32 + lr)) * 16 + lg * 8);

    const short8* bptr = reinterpret_cast<const short8*>(
        Bcols + ((size_t)(batch * NPTS + colbase + lr)) * 16 + lg * 8);
    const float16 zero16 = {0.f, 0.f, 0.f, 0.f, 0.f, 0.f, 0.f, 0.f,
                            0.f, 0.f, 0.f, 0.f, 0.f, 0.f, 0.f, 0.f};

    float mx0 = -INFINITY, mx1 = -INFINITY;

    const int NT = NPTS / 4 / 32;    // 64 col-tiles; tile stride = 64 short8
    short8 b0 = bptr[0];
    short8 b1 = bptr[64];

    for (int ct = 0; ct < NT; ct += 2) {
        // prefetch next pair (uniform clamped index -> scalar select, no branch)
        const int nct = (ct + 2 < NT) ? ct + 2 : NT - 2;
        const short8 n0 = bptr[(size_t)nct * 64];
        const short8 n1 = bptr[(size_t)(nct + 1) * 64];

        float16 d0 = __builtin_amdgcn_mfma_f32_32x32x16_bf16(b0, a0, zero16, 0, 0, 0);
        float16 d1 = __builtin_amdgcn_mfma_f32_32x32x16_bf16(b0, a1, zero16, 0, 0, 0);
#pragma unroll
        for (int j = 0; j < 8; ++j) {
            mx0 = fmaxf(fmaxf(d0[2 * j], d0[2 * j + 1]), mx0);  // v_max3
            mx1 = fmaxf(fmaxf(d1[2 * j], d1[2 * j + 1]), mx1);
        }
        float16 d2 = __builtin_amdgcn_mfma_f32_32x32x16_bf16(b1, a0, zero16, 0, 0, 0);
        float16 d3 = __builtin_amdgcn_mfma_f32_32x32x16_bf16(b1, a1, zero16, 0, 0, 0);
#pragma unroll
        for (int j = 0; j < 8; ++j) {
            mx0 = fmaxf(fmaxf(d2[2 * j], d2[2 * j + 1]), mx0);
            mx1 = fmaxf(fmaxf(d3[2 * j], d3[2 * j + 1]), mx1);
        }
        b0 = n0; b1 = n1;
    }

    // lanes l and l+32 hold maxes over disjoint col subsets for the same row
    mx0 = fmaxf(mx0, __shfl_xor(mx0, 32, 64));
    mx1 = fmaxf(mx1, __shfl_xor(mx1, 32, 64));
    if (lane < 32) {
        atomicMax(&smax[batch * NPTS + row0 + lane],      map_f(mx0));
        atomicMax(&smax[batch * NPTS + row0 + 32 + lane], map_f(mx1));
    }
}

// ---------------------------------------------------------------------------
// deterministic 2-stage final sum: loss = 2 * sum_i (norms[i] - unmap(smax[i]))
// ---------------------------------------------------------------------------
__global__ __launch_bounds__(256)
void final_stage1(const float* __restrict__ norms, const uint32* __restrict__ smax,
                  float* __restrict__ partials)
{
    const int base = blockIdx.x * 1024;
    float s = 0.f;
    for (int k = threadIdx.x; k < 1024; k += 256) {
        const int i = base + k;
        s += norms[i] - unmap_f(smax[i]);
    }
#pragma unroll
    for (int off = 32; off; off >>= 1) s += __shfl_down(s, off, 64);
    __shared__ float ws4[4];
    if ((threadIdx.x & 63) == 0) ws4[threadIdx.x >> 6] = s;
    __syncthreads();
    if (threadIdx.x == 0) partials[blockIdx.x] = (ws4[0] + ws4[1]) + (ws4[2] + ws4[3]);
}

__global__ void final_stage2(const float* __restrict__ partials, float* __restrict__ out)
{
    float s = partials[threadIdx.x] + partials[threadIdx.x + 64];
#pragma unroll
    for (int off = 32; off; off >>= 1) s += __shfl_down(s, off, 64);
    if (threadIdx.x == 0) *out = 2.0f * s;
}

extern "C" void kernel_launch(void* const* d_in, const int* in_sizes, int n_in,
                              void* d_out, int out_size, void* d_ws, size_t ws_size,
                              hipStream_t stream) {
    const float* preds = (const float*)d_in[0];  // [B, M, 3]
    const float* gts   = (const float*)d_in[1];  // [B, N, 3]

    char* w = (char*)d_ws;
    float*  norms = (float*)w;                                   // 512 KiB  [haa|hbb]
    uint32* smax  = (uint32*)(w + 8 * (size_t)NPT_TOT);          // 512 KiB  [smax1|smax2]
    unsigned short* AG = (unsigned short*)(w + 16 * (size_t)NPT_TOT);  // 2 MiB each
    unsigned short* BG = AG + 16 * (size_t)NPT_TOT;
    unsigned short* AP = BG + 16 * (size_t)NPT_TOT;
    unsigned short* BP = AP + 16 * (size_t)NPT_TOT;
    float* partials = (float*)(w + 16 * (size_t)NPT_TOT + 4 * 32 * (size_t)NPT_TOT);

    prepass<<<(2 * NPT_TOT) / 256, 256, 0, stream>>>(gts, preds, norms, smax,
                                                     AG, BG, AP, BP);

    dim3 grid(4, NPTS / 256, BATCH);  // 4 col-chunks x 32 row-groups x 8 batches
    // loss_2: rows = gts, cols = preds (col-form carries h_pred)
    chamfer_mfma<<<grid, 256, 0, stream>>>(AG, BP, smax);
    // loss_1: rows = preds, cols = gts
    chamfer_mfma<<<grid, 256, 0, stream>>>(AP, BG, smax + NPT_TOT);

    final_stage1<<<128, 256, 0, stream>>>(norms, smax, partials);
    final_stage2<<<1, 64, 0, stream>>>(partials, (float*)d_out);
}

// Round 5
// 66.691 us; speedup vs baseline: 3.1603x; 1.1174x over previous
//
#include <hip/hip_runtime.h>
#include <hip/hip_bf16.h>

#define BATCH 8
#define NPTS  8192
#define NPT_TOT (BATCH * NPTS)   // 65536 points per cloud

typedef __attribute__((ext_vector_type(8)))  short short8;
typedef __attribute__((ext_vector_type(16))) float float16;
typedef unsigned int uint32;

// order-preserving float->uint map for atomicMax
__device__ __forceinline__ uint32 map_f(float f) {
    int i = __float_as_int(f);
    return (uint32)(i ^ ((i >> 31) | 0x80000000));
}
__device__ __forceinline__ float unmap_f(uint32 u) {
    int i = (u & 0x80000000u) ? (int)(u ^ 0x80000000u) : (int)~u;
    return __int_as_float(i);
}

__device__ __forceinline__ unsigned short bf16_of(float f) {
    __hip_bfloat16 h = __float2bfloat16(f);
    return *reinterpret_cast<unsigned short*>(&h);
}
__device__ __forceinline__ float f_of_bf16(unsigned short u) {
    __hip_bfloat16 h = *reinterpret_cast<__hip_bfloat16*>(&u);
    return __bfloat162float(h);
}
__device__ __forceinline__ uint32 pk(unsigned short lo, unsigned short hi) {
    return (uint32)lo | ((uint32)hi << 16);
}
// guaranteed single-instruction 3-input max
__device__ __forceinline__ float max3f(float a, float b, float c) {
    float d;
    asm("v_max3_f32 %0, %1, %2, %3" : "=v"(d) : "v"(a), "v"(b), "v"(c));
    return d;
}

// ---------------------------------------------------------------------------
// prepass: per point build K-major 16-slot vectors
//   Row-form (A): [xh yh zh | xl yl zl | xh yh zh | xl yl zl | 1 1 0 0]
//   Col-form (B): [xh yh zh | xh yh zh | xl yl zl | xl yl zl | -hh -hl 0 0]
// sum_k Row[k](a)*Col[k](b) = (ah+al).(bh+bl) - 0.5|b|^2
// ---------------------------------------------------------------------------
__global__ __launch_bounds__(256)
void prepass(const float* __restrict__ gts, const float* __restrict__ preds,
             float* __restrict__ norms, uint32* __restrict__ smax,
             unsigned short* __restrict__ AG, unsigned short* __restrict__ BG,
             unsigned short* __restrict__ AP, unsigned short* __restrict__ BP)
{
    int i = blockIdx.x * blockDim.x + threadIdx.x;
    if (i >= 2 * NPT_TOT) return;
    const bool isGt = i < NPT_TOT;
    const int j = isGt ? i : i - NPT_TOT;
    const float* src = (isGt ? gts : preds) + 3 * (size_t)j;
    const float x = src[0], y = src[1], z = src[2];
    const float h = 0.5f * (x * x + y * y + z * z);
    norms[i] = h;       // [haa | hbb]
    smax[i]  = 0u;      // mapped: below every real value

    const unsigned short xh = bf16_of(x), yh = bf16_of(y), zh = bf16_of(z);
    const unsigned short xl = bf16_of(x - f_of_bf16(xh));
    const unsigned short yl = bf16_of(y - f_of_bf16(yh));
    const unsigned short zl = bf16_of(z - f_of_bf16(zh));
    const unsigned short nhh = bf16_of(-h);
    const unsigned short nhl = bf16_of(-h - f_of_bf16(nhh));
    const unsigned short one = 0x3F80;

    unsigned short* A = (isGt ? AG : AP) + (size_t)j * 16;
    unsigned short* Bf = (isGt ? BG : BP) + (size_t)j * 16;

    uint4 av0 = { pk(xh, yh), pk(zh, xl), pk(yl, zl), pk(xh, yh) };
    uint4 av1 = { pk(zh, xl), pk(yl, zl), pk(one, one), 0u };
    *reinterpret_cast<uint4*>(A)     = av0;
    *reinterpret_cast<uint4*>(A + 8) = av1;

    uint4 bv0 = { pk(xh, yh), pk(zh, xh), pk(yh, zh), pk(xl, yl) };
    uint4 bv1 = { pk(zl, xl), pk(yl, zl), pk(nhh, nhl), 0u };
    *reinterpret_cast<uint4*>(Bf)     = bv0;
    *reinterpret_cast<uint4*>(Bf + 8) = bv1;
}

// ---------------------------------------------------------------------------
// main: swapped-operand MFMA (streamed cols = A-operand, wave's 64 rows =
// B-operand) so each lane's D regs are 16 col-points of ONE row; column max
// is an in-register v_max3 chain. 4 col-tiles per iteration with two named
// buffer pairs (no rotate copies), unconditional prefetch into padded B.
// ---------------------------------------------------------------------------
#define NT 32            // col-tiles per wave (grid.x = 8 -> 1024 cols/block)
__global__ __launch_bounds__(256)
void chamfer_mfma(const unsigned short* __restrict__ Arows,
                  const unsigned short* __restrict__ Bcols,
                  uint32* __restrict__ smax)
{
    const int lane  = threadIdx.x & 63;
    const int wid   = threadIdx.x >> 6;
    const int batch = blockIdx.z;
    const int row0  = blockIdx.y * 256 + wid * 64;
    const int colbase = blockIdx.x * (NT * 32);    // 1024 cols per block

    const int lr = lane & 31;        // point within tile
    const int lg = lane >> 5;        // K-half group

    // row-points as MFMA B-operand fragments
    const short8 a0 = *reinterpret_cast<const short8*>(
        Arows + ((size_t)(batch * NPTS + row0 + lr)) * 16 + lg * 8);
    const short8 a1 = *reinterpret_cast<const short8*>(
        Arows + ((size_t)(batch * NPTS + row0 + 32 + lr)) * 16 + lg * 8);

    const short8* bptr = reinterpret_cast<const short8*>(
        Bcols + ((size_t)(batch * NPTS + colbase + lr)) * 16 + lg * 8);
    const float16 zero16 = {0.f, 0.f, 0.f, 0.f, 0.f, 0.f, 0.f, 0.f,
                            0.f, 0.f, 0.f, 0.f, 0.f, 0.f, 0.f, 0.f};

    float mx0 = -INFINITY, mx1 = -INFINITY;

    // tile t of 32 points lives at bptr[t*64] (point = 2 short8)
    short8 bA0 = bptr[0],   bA1 = bptr[64];
    short8 bB0 = bptr[128], bB1 = bptr[192];

    for (int ct = 0; ct < NT; ct += 4) {
        const short8* p = bptr + (size_t)ct * 64;

        float16 d0 = __builtin_amdgcn_mfma_f32_32x32x16_bf16(bA0, a0, zero16, 0, 0, 0);
        float16 d1 = __builtin_amdgcn_mfma_f32_32x32x16_bf16(bA0, a1, zero16, 0, 0, 0);
        float16 d2 = __builtin_amdgcn_mfma_f32_32x32x16_bf16(bA1, a0, zero16, 0, 0, 0);
        float16 d3 = __builtin_amdgcn_mfma_f32_32x32x16_bf16(bA1, a1, zero16, 0, 0, 0);
        // unconditional prefetch (pad guarantees in-bounds; last values unused)
        bA0 = p[256]; bA1 = p[320];                 // tiles ct+4, ct+5
#pragma unroll
        for (int j = 0; j < 8; ++j) {
            mx0 = max3f(d0[2 * j], d0[2 * j + 1], mx0);
            mx1 = max3f(d1[2 * j], d1[2 * j + 1], mx1);
            mx0 = max3f(d2[2 * j], d2[2 * j + 1], mx0);
            mx1 = max3f(d3[2 * j], d3[2 * j + 1], mx1);
        }

        float16 e0 = __builtin_amdgcn_mfma_f32_32x32x16_bf16(bB0, a0, zero16, 0, 0, 0);
        float16 e1 = __builtin_amdgcn_mfma_f32_32x32x16_bf16(bB0, a1, zero16, 0, 0, 0);
        float16 e2 = __builtin_amdgcn_mfma_f32_32x32x16_bf16(bB1, a0, zero16, 0, 0, 0);
        float16 e3 = __builtin_amdgcn_mfma_f32_32x32x16_bf16(bB1, a1, zero16, 0, 0, 0);
        bB0 = p[384]; bB1 = p[448];                 // tiles ct+6, ct+7
#pragma unroll
        for (int j = 0; j < 8; ++j) {
            mx0 = max3f(e0[2 * j], e0[2 * j + 1], mx0);
            mx1 = max3f(e1[2 * j], e1[2 * j + 1], mx1);
            mx0 = max3f(e2[2 * j], e2[2 * j + 1], mx0);
            mx1 = max3f(e3[2 * j], e3[2 * j + 1], mx1);
        }
    }

    // lanes l and l+32 hold maxes over disjoint col subsets for the same row
    mx0 = fmaxf(mx0, __shfl_xor(mx0, 32, 64));
    mx1 = fmaxf(mx1, __shfl_xor(mx1, 32, 64));
    if (lane < 32) {
        atomicMax(&smax[batch * NPTS + row0 + lane],      map_f(mx0));
        atomicMax(&smax[batch * NPTS + row0 + 32 + lane], map_f(mx1));
    }
}

// ---------------------------------------------------------------------------
// deterministic 2-stage final sum: loss = 2 * sum_i (norms[i] - unmap(smax[i]))
// ---------------------------------------------------------------------------
__global__ __launch_bounds__(256)
void final_stage1(const float* __restrict__ norms, const uint32* __restrict__ smax,
                  float* __restrict__ partials)
{
    const int base = blockIdx.x * 1024;
    float s = 0.f;
    for (int k = threadIdx.x; k < 1024; k += 256) {
        const int i = base + k;
        s += norms[i] - unmap_f(smax[i]);
    }
#pragma unroll
    for (int off = 32; off; off >>= 1) s += __shfl_down(s, off, 64);
    __shared__ float ws4[4];
    if ((threadIdx.x & 63) == 0) ws4[threadIdx.x >> 6] = s;
    __syncthreads();
    if (threadIdx.x == 0) partials[blockIdx.x] = (ws4[0] + ws4[1]) + (ws4[2] + ws4[3]);
}

__global__ void final_stage2(const float* __restrict__ partials, float* __restrict__ out)
{
    float s = partials[threadIdx.x] + partials[threadIdx.x + 64];
#pragma unroll
    for (int off = 32; off; off >>= 1) s += __shfl_down(s, off, 64);
    if (threadIdx.x == 0) *out = 2.0f * s;
}

extern "C" void kernel_launch(void* const* d_in, const int* in_sizes, int n_in,
                              void* d_out, int out_size, void* d_ws, size_t ws_size,
                              hipStream_t stream) {
    const float* preds = (const float*)d_in[0];  // [B, M, 3]
    const float* gts   = (const float*)d_in[1];  // [B, N, 3]

    char* w = (char*)d_ws;
    float*  norms = (float*)w;                                   // 512 KiB  [haa|hbb]
    uint32* smax  = (uint32*)(w + 8 * (size_t)NPT_TOT);          // 512 KiB  [smax1|smax2]
    // packed arrays: 2 MiB each + 8 KiB pad so unconditional tile prefetch
    // (up to 4 tiles = 4 KiB past the end) stays in-bounds
    const size_t PITCH = 32 * (size_t)NPT_TOT + 8192;
    unsigned short* AG = (unsigned short*)(w + 16 * (size_t)NPT_TOT);
    unsigned short* BG = (unsigned short*)((char*)AG + PITCH);
    unsigned short* AP = (unsigned short*)((char*)AG + 2 * PITCH);
    unsigned short* BP = (unsigned short*)((char*)AG + 3 * PITCH);
    float* partials = (float*)((char*)AG + 4 * PITCH);

    prepass<<<(2 * NPT_TOT) / 256, 256, 0, stream>>>(gts, preds, norms, smax,
                                                     AG, BG, AP, BP);

    dim3 grid(8, NPTS / 256, BATCH);  // 8 col-chunks x 32 row-groups x 8 batches
    // loss_2: rows = gts, cols = preds (col-form carries h_pred)
    chamfer_mfma<<<grid, 256, 0, stream>>>(AG, BP, smax);
    // loss_1: rows = preds, cols = gts
    chamfer_mfma<<<grid, 256, 0, stream>>>(AP, BG, smax + NPT_TOT);

    final_stage1<<<128, 256, 0, stream>>>(norms, smax, partials);
    final_stage2<<<1, 64, 0, stream>>>(partials, (float*)d_out);
}